// Round 7
// baseline (150.550 us; speedup 1.0000x reference)
//
#include <hip/hip_runtime.h>
#include <hip/hip_bf16.h>

// LoRA conv experts, algebraically collapsed into ONE rank-64 separable pair:
//   W1[(e,r)][kx*256+c] = p_e * w_in[e,r,c,0,kx]    (64 x 768)
//   W2[o][ky*64+(e,r)]  = w_out[e,o,r,ky,0]         (256 x 192)
// R7 = R4's exact proven LDS layout/swizzle, re-partitioned for occupancy:
// block = (b, y-stripe of 2, n-half of 32). grid 1024 = 4 blocks/CU exactly;
// LDS 34.8 KB (xs[34][264] + hs[32][264]) -> 4 blocks/CU. W1/W2 fragments
// streamed from L2 (not hoisted) to keep VGPR <= 128 (16 waves/CU cap).

typedef __bf16 bf16x8 __attribute__((ext_vector_type(8)));
typedef __bf16 bf16x4 __attribute__((ext_vector_type(4)));
typedef float  f32x4  __attribute__((ext_vector_type(4)));

#define CIN_  256
#define COUT_ 256
#define M1    64
#define K1    768
#define K2    192
#define CS    264     // xs row stride (shorts) — R4 class (132 dw ≡ 4 mod 32)
#define HSS   264     // hs row stride (shorts)

static __device__ __forceinline__ unsigned short f2bf(float f) {
    union { float f; unsigned u; } v; v.f = f;
    unsigned r = v.u + 0x7FFFu + ((v.u >> 16) & 1u);
    return (unsigned short)(r >> 16);
}

// ------------- prep: fold probs, reorder, cast to bf16 (W1, W2) -------------
__global__ void prep_weights(const float* __restrict__ probs,
                             const float* __restrict__ w_in,
                             const float* __restrict__ w_out,
                             unsigned short* __restrict__ W1,
                             unsigned short* __restrict__ W2) {
    int idx = blockIdx.x * blockDim.x + threadIdx.x;
    if (idx < M1 * K1) {
        int er = idx / K1, rem = idx % K1;
        int kx = rem / CIN_, c = rem % CIN_;
        int e = er >> 3;
        W1[idx] = f2bf(probs[e] * w_in[(er * CIN_ + c) * 3 + kx]);
    } else {
        int i2 = idx - M1 * K1;   // grid sized exactly (M1*K1 == COUT_*K2)
        int o = i2 / K2, rem = i2 % K2;
        int ky = rem / M1, er = rem % M1;
        int e = er >> 3, r = er & 7;
        W2[i2] = f2bf(w_out[((e * COUT_ + o) * 8 + r) * 3 + ky]);
    }
}

// ----------------------------- fused conv kernel -----------------------------
// grid = 16 b * 32 y-stripes * 2 n-halves = 1024 blocks, 256 threads (4 waves).
__global__ __launch_bounds__(256, 4)
void fused_kernel(const float* __restrict__ x,
                  const unsigned short* __restrict__ W1,
                  const unsigned short* __restrict__ W2,
                  float* __restrict__ out) {
    __shared__ unsigned short xs[34 * CS];   // row ns = nl+1, nl = -1..32 (local n)
    __shared__ unsigned short hs[32 * HSS];  // [nl][(yy*64+m) ^ ((nl&7)<<3)]
    const int bid  = blockIdx.x;
    const int b    = bid >> 6;
    const int s    = bid & 63;
    const int y0   = (s >> 1) << 1;
    const int nh   = s & 1;
    const int nbase = nh << 5;               // 0 or 32
    const int tid  = threadIdx.x;
    const int lane = tid & 63;
    const int wave = tid >> 6;               // m-tile (phase 1) / o-group (phase 2)
    const int g    = lane >> 4;
    const int lr   = lane & 15;

    // staging map: c-row base = tid>>3 (0..31), n-quad nl = (tid&7)*4,
    // swizzle (R4 quad-key): swzt = ((nl>>2)&7)<<3 = (tid&7)<<3
    const int cr   = tid >> 3;
    const int n4   = (tid & 7) << 2;
    const int swzt = (tid & 7) << 3;

    // ---------------- phase 1: 4 h-rows y = y0-1 .. y0+2 ----------------
    for (int yy = 0; yy < 4; ++yy) {
        const int y = y0 - 1 + yy;
        const bool yok = ((unsigned)y < 64u);
        const int ysafe = yok ? y : 0;
        __syncthreads();                      // xs free

        // halo columns nl=-1 (row 0, key 7 -> cx = c^56) and nl=32 (row 33, key 0)
        {
            const float* xcol = x + ((b * CIN_ + tid) * 64 + ysafe) * 64;
            int ngl = nbase - 1, ngr = nbase + 32;
            float vl = (yok && ngl >= 0) ? xcol[ngl < 0 ? 0 : ngl] : 0.f;
            float vr = (yok && ngr < 64) ? xcol[ngr > 63 ? 63 : ngr] : 0.f;
            xs[0 * CS + (tid ^ 56)] = f2bf(vl);
            xs[33 * CS + tid]       = f2bf(vr);
        }
        // main 32 n-cols: 8 float4/thread, c = cr + 32*chunk
        const float* xb = x + ((b * CIN_ + cr) * 64 + ysafe) * 64 + nbase + n4;
        #pragma unroll
        for (int r = 0; r < 2; ++r) {
            float4 ld[4];
            if (yok) {
                #pragma unroll
                for (int q = 0; q < 4; ++q)
                    ld[q] = *(const float4*)(xb + (r * 4 + q) * 32 * 4096);
            } else {
                #pragma unroll
                for (int q = 0; q < 4; ++q) ld[q] = make_float4(0.f, 0.f, 0.f, 0.f);
            }
            #pragma unroll
            for (int q = 0; q < 4; ++q) {
                int cx = (cr + 32 * (r * 4 + q)) ^ swzt;
                unsigned short* wr = &xs[(n4 + 1) * CS + cx];
                wr[0 * CS] = f2bf(ld[q].x);
                wr[1 * CS] = f2bf(ld[q].y);
                wr[2 * CS] = f2bf(ld[q].z);
                wr[3 * CS] = f2bf(ld[q].w);
            }
        }
        __syncthreads();                      // xs ready

        f32x4 acc[2];
        acc[0] = (f32x4){0.f, 0.f, 0.f, 0.f};
        acc[1] = (f32x4){0.f, 0.f, 0.f, 0.f};

        #pragma unroll
        for (int kx = 0; kx < 3; ++kx) {
            // stream this kx's W1 A-frags (32 VGPR, L2-hot)
            bf16x8 w1k[8];
            const unsigned short* w1p = W1 + (wave * 16 + lr) * K1 + kx * CIN_ + g * 8;
            #pragma unroll
            for (int cc = 0; cc < 8; ++cc)
                w1k[cc] = *(const bf16x8*)(w1p + cc * 32);
            #pragma unroll
            for (int cc = 0; cc < 8; ++cc) {
                int co = cc * 32 + g * 8;
                #pragma unroll
                for (int nt = 0; nt < 2; ++nt) {
                    int nl = nt * 16 + lr + kx - 1;   // local n of this frag
                    bf16x8 bfv = *(const bf16x8*)&xs[(nl + 1) * CS +
                                                     (co ^ ((((nl) >> 2) & 7) << 3))];
                    acc[nt] = __builtin_amdgcn_mfma_f32_16x16x32_bf16(
                        w1k[cc], bfv, acc[nt], 0, 0, 0);
                }
            }
        }
        // D: col=lr (n), row=g*4+r2 (m). b64 into hs, R4 swizzle key (nl&7).
        #pragma unroll
        for (int nt = 0; nt < 2; ++nt) {
            int nl = nt * 16 + lr;
            int col = (yy * 64 + wave * 16 + g * 4) ^ ((nl & 7) << 3);
            bf16x4 pk;
            #pragma unroll
            for (int r2 = 0; r2 < 4; ++r2) pk[r2] = (__bf16)acc[nt][r2];
            *(bf16x4*)&hs[nl * HSS + col] = pk;
        }
    }
    __syncthreads();                          // hs complete

    // ---------------- phase 2: 2 output rows ----------------
    #pragma unroll
    for (int ry = 0; ry < 2; ++ry) {
        f32x4 acc2[4][2];
        #pragma unroll
        for (int ot = 0; ot < 4; ++ot)
            #pragma unroll
            for (int nt = 0; nt < 2; ++nt) acc2[ot][nt] = (f32x4){0.f, 0.f, 0.f, 0.f};

        #pragma unroll
        for (int kc = 0; kc < 6; ++kc) {
            bf16x8 bfrag[2];
            #pragma unroll
            for (int nt = 0; nt < 2; ++nt) {
                int nl = nt * 16 + lr;
                bfrag[nt] = *(const bf16x8*)&hs[nl * HSS +
                    ((ry * 64 + kc * 32 + g * 8) ^ ((nl & 7) << 3))];
            }
            #pragma unroll
            for (int ot = 0; ot < 4; ++ot) {
                bf16x8 af = *(const bf16x8*)(W2 + ((wave * 4 + ot) * 16 + lr) * K2 +
                                             kc * 32 + g * 8);
                #pragma unroll
                for (int nt = 0; nt < 2; ++nt)
                    acc2[ot][nt] = __builtin_amdgcn_mfma_f32_16x16x32_bf16(
                        af, bfrag[nt], acc2[ot][nt], 0, 0, 0);
            }
        }

        const int yo = y0 + ry;
        #pragma unroll
        for (int ot = 0; ot < 4; ++ot) {
            #pragma unroll
            for (int r2 = 0; r2 < 4; ++r2) {
                int o = (wave * 4 + ot) * 16 + g * 4 + r2;
                float* orow = out + ((b * COUT_ + o) * 64 + yo) * 64 + nbase;
                #pragma unroll
                for (int nt = 0; nt < 2; ++nt)
                    orow[nt * 16 + lr] = acc2[ot][nt][r2];
            }
        }
    }
}

extern "C" void kernel_launch(void* const* d_in, const int* in_sizes, int n_in,
                              void* d_out, int out_size, void* d_ws, size_t ws_size,
                              hipStream_t stream) {
    const float* x     = (const float*)d_in[0];   // [16,256,64,64]
    const float* probs = (const float*)d_in[1];   // [8]
    const float* w_in  = (const float*)d_in[2];   // [8,8,256,1,3]
    const float* w_out = (const float*)d_in[3];   // [8,256,8,3,1]
    float* out = (float*)d_out;                   // [16,256,64,64] f32

    unsigned short* W1 = (unsigned short*)d_ws;   // 64*768 bf16
    unsigned short* W2 = W1 + M1 * K1;            // 256*192 bf16

    prep_weights<<<384, 256, 0, stream>>>(probs, w_in, w_out, W1, W2);
    fused_kernel<<<16 * 64, 256, 0, stream>>>(x, W1, W2, out);
}

// Round 8
// 79.963 us; speedup vs baseline: 1.8828x; 1.8828x over previous
//
#include <hip/hip_runtime.h>
#include <hip/hip_bf16.h>

// LoRA conv experts, algebraically collapsed into ONE rank-64 separable pair:
//   W1[(e,r)][kx*256+c] = p_e * w_in[e,r,c,0,kx]    (64 x 768)
//   W2[o][ky*64+(e,r)]  = w_out[e,o,r,ky,0]         (256 x 192)
// R8 = R7 partition (block = (b, y-stripe of 2, n-half of 32); 1024 blocks;
// 35 KB LDS -> 4 blocks/CU) with the VGPR-64 forcing REMOVED:
// __launch_bounds__(256) plain, so the allocator lands in the <=128 tier
// naturally and nothing spills (R7's 150us was 100+ MB of scratch traffic
// from the forced 64-VGPR tier, NOT the partition).

typedef __bf16 bf16x8 __attribute__((ext_vector_type(8)));
typedef __bf16 bf16x4 __attribute__((ext_vector_type(4)));
typedef float  f32x4  __attribute__((ext_vector_type(4)));

#define CIN_  256
#define COUT_ 256
#define M1    64
#define K1    768
#define K2    192
#define CS    264     // xs row stride (shorts) — R4-proven (132 dw = 4 mod 32)
#define HSS   264     // hs row stride (shorts)

static __device__ __forceinline__ unsigned short f2bf(float f) {
    union { float f; unsigned u; } v; v.f = f;
    unsigned r = v.u + 0x7FFFu + ((v.u >> 16) & 1u);
    return (unsigned short)(r >> 16);
}

// ------------- prep: fold probs, reorder, cast to bf16 (W1, W2) -------------
__global__ void prep_weights(const float* __restrict__ probs,
                             const float* __restrict__ w_in,
                             const float* __restrict__ w_out,
                             unsigned short* __restrict__ W1,
                             unsigned short* __restrict__ W2) {
    int idx = blockIdx.x * blockDim.x + threadIdx.x;
    if (idx < M1 * K1) {
        int er = idx / K1, rem = idx % K1;
        int kx = rem / CIN_, c = rem % CIN_;
        int e = er >> 3;
        W1[idx] = f2bf(probs[e] * w_in[(er * CIN_ + c) * 3 + kx]);
    } else {
        int i2 = idx - M1 * K1;   // grid sized exactly (M1*K1 == COUT_*K2)
        int o = i2 / K2, rem = i2 % K2;
        int ky = rem / M1, er = rem % M1;
        int e = er >> 3, r = er & 7;
        W2[i2] = f2bf(w_out[((e * COUT_ + o) * 8 + r) * 3 + ky]);
    }
}

// ----------------------------- fused conv kernel -----------------------------
// grid = 16 b * 32 y-stripes * 2 n-halves = 1024 blocks, 256 threads (4 waves).
__global__ __launch_bounds__(256)
void fused_kernel(const float* __restrict__ x,
                  const unsigned short* __restrict__ W1,
                  const unsigned short* __restrict__ W2,
                  float* __restrict__ out) {
    __shared__ unsigned short xs[34 * CS];   // row ns = nl+1, nl = -1..32 (local n)
    __shared__ unsigned short hs[32 * HSS];  // [nl][(yy*64+m) ^ ((nl&7)<<3)]
    const int bid  = blockIdx.x;
    const int b    = bid >> 6;
    const int s    = bid & 63;
    const int y0   = (s >> 1) << 1;
    const int nh   = s & 1;
    const int nbase = nh << 5;               // 0 or 32
    const int tid  = threadIdx.x;
    const int lane = tid & 63;
    const int wave = tid >> 6;               // m-tile (phase 1) / o-group (phase 2)
    const int g    = lane >> 4;
    const int lr   = lane & 15;

    // staging map: c-row base = tid>>3 (0..31), n-quad nl = (tid&7)*4,
    // swizzle (R4 quad-key): swzt = ((nl>>2)&7)<<3 = (tid&7)<<3
    const int cr   = tid >> 3;
    const int n4   = (tid & 7) << 2;
    const int swzt = (tid & 7) << 3;

    // ---------------- phase 1: 4 h-rows y = y0-1 .. y0+2 ----------------
    for (int yy = 0; yy < 4; ++yy) {
        const int y = y0 - 1 + yy;
        const bool yok = ((unsigned)y < 64u);
        const int ysafe = yok ? y : 0;
        __syncthreads();                      // xs free

        // halo columns nl=-1 (row 0, quad-key 7 -> cx = c^56) and nl=32 (row 33, key 0)
        {
            const float* xcol = x + ((b * CIN_ + tid) * 64 + ysafe) * 64;
            int ngl = nbase - 1, ngr = nbase + 32;
            float vl = (yok && ngl >= 0) ? xcol[ngl < 0 ? 0 : ngl] : 0.f;
            float vr = (yok && ngr < 64) ? xcol[ngr > 63 ? 63 : ngr] : 0.f;
            xs[0 * CS + (tid ^ 56)] = f2bf(vl);
            xs[33 * CS + tid]       = f2bf(vr);
        }
        // main 32 n-cols: 8 float4/thread, c = cr + 32*chunk
        const float* xb = x + ((b * CIN_ + cr) * 64 + ysafe) * 64 + nbase + n4;
        #pragma unroll
        for (int r = 0; r < 2; ++r) {
            float4 ld[4];
            if (yok) {
                #pragma unroll
                for (int q = 0; q < 4; ++q)
                    ld[q] = *(const float4*)(xb + (r * 4 + q) * 32 * 4096);
            } else {
                #pragma unroll
                for (int q = 0; q < 4; ++q) ld[q] = make_float4(0.f, 0.f, 0.f, 0.f);
            }
            #pragma unroll
            for (int q = 0; q < 4; ++q) {
                int cx = (cr + 32 * (r * 4 + q)) ^ swzt;
                unsigned short* wr = &xs[(n4 + 1) * CS + cx];
                wr[0 * CS] = f2bf(ld[q].x);
                wr[1 * CS] = f2bf(ld[q].y);
                wr[2 * CS] = f2bf(ld[q].z);
                wr[3 * CS] = f2bf(ld[q].w);
            }
        }
        __syncthreads();                      // xs ready

        f32x4 acc[2];
        acc[0] = (f32x4){0.f, 0.f, 0.f, 0.f};
        acc[1] = (f32x4){0.f, 0.f, 0.f, 0.f};

        #pragma unroll
        for (int kx = 0; kx < 3; ++kx) {
            // stream this kx's W1 A-frags (32 VGPR, L2-hot)
            bf16x8 w1k[8];
            const unsigned short* w1p = W1 + (wave * 16 + lr) * K1 + kx * CIN_ + g * 8;
            #pragma unroll
            for (int cc = 0; cc < 8; ++cc)
                w1k[cc] = *(const bf16x8*)(w1p + cc * 32);
            #pragma unroll
            for (int cc = 0; cc < 8; ++cc) {
                int co = cc * 32 + g * 8;
                #pragma unroll
                for (int nt = 0; nt < 2; ++nt) {
                    int nl = nt * 16 + lr + kx - 1;   // local n of this frag
                    bf16x8 bfv = *(const bf16x8*)&xs[(nl + 1) * CS +
                                                     (co ^ ((((nl) >> 2) & 7) << 3))];
                    acc[nt] = __builtin_amdgcn_mfma_f32_16x16x32_bf16(
                        w1k[cc], bfv, acc[nt], 0, 0, 0);
                }
            }
        }
        // D: col=lr (n), row=g*4+r2 (m). b64 into hs, R4 swizzle key (nl&7).
        #pragma unroll
        for (int nt = 0; nt < 2; ++nt) {
            int nl = nt * 16 + lr;
            int col = (yy * 64 + wave * 16 + g * 4) ^ ((nl & 7) << 3);
            bf16x4 pk;
            #pragma unroll
            for (int r2 = 0; r2 < 4; ++r2) pk[r2] = (__bf16)acc[nt][r2];
            *(bf16x4*)&hs[nl * HSS + col] = pk;
        }
    }
    __syncthreads();                          // hs complete

    // ---------------- phase 2: 2 output rows ----------------
    #pragma unroll
    for (int ry = 0; ry < 2; ++ry) {
        f32x4 acc2[4][2];
        #pragma unroll
        for (int ot = 0; ot < 4; ++ot)
            #pragma unroll
            for (int nt = 0; nt < 2; ++nt) acc2[ot][nt] = (f32x4){0.f, 0.f, 0.f, 0.f};

        #pragma unroll
        for (int kc = 0; kc < 6; ++kc) {
            bf16x8 bfrag[2];
            #pragma unroll
            for (int nt = 0; nt < 2; ++nt) {
                int nl = nt * 16 + lr;
                bfrag[nt] = *(const bf16x8*)&hs[nl * HSS +
                    ((ry * 64 + kc * 32 + g * 8) ^ ((nl & 7) << 3))];
            }
            #pragma unroll
            for (int ot = 0; ot < 4; ++ot) {
                bf16x8 af = *(const bf16x8*)(W2 + ((wave * 4 + ot) * 16 + lr) * K2 +
                                             kc * 32 + g * 8);
                #pragma unroll
                for (int nt = 0; nt < 2; ++nt)
                    acc2[ot][nt] = __builtin_amdgcn_mfma_f32_16x16x32_bf16(
                        af, bfrag[nt], acc2[ot][nt], 0, 0, 0);
            }
        }

        const int yo = y0 + ry;
        #pragma unroll
        for (int ot = 0; ot < 4; ++ot) {
            #pragma unroll
            for (int r2 = 0; r2 < 4; ++r2) {
                int o = (wave * 4 + ot) * 16 + g * 4 + r2;
                float* orow = out + ((b * COUT_ + o) * 64 + yo) * 64 + nbase;
                #pragma unroll
                for (int nt = 0; nt < 2; ++nt)
                    orow[nt * 16 + lr] = acc2[ot][nt][r2];
            }
        }
    }
}

extern "C" void kernel_launch(void* const* d_in, const int* in_sizes, int n_in,
                              void* d_out, int out_size, void* d_ws, size_t ws_size,
                              hipStream_t stream) {
    const float* x     = (const float*)d_in[0];   // [16,256,64,64]
    const float* probs = (const float*)d_in[1];   // [8]
    const float* w_in  = (const float*)d_in[2];   // [8,8,256,1,3]
    const float* w_out = (const float*)d_in[3];   // [8,256,8,3,1]
    float* out = (float*)d_out;                   // [16,256,64,64] f32

    unsigned short* W1 = (unsigned short*)d_ws;   // 64*768 bf16
    unsigned short* W2 = W1 + M1 * K1;            // 256*192 bf16

    prep_weights<<<384, 256, 0, stream>>>(probs, w_in, w_out, W1, W2);
    fused_kernel<<<16 * 64, 256, 0, stream>>>(x, W1, W2, out);
}